// Round 1
// baseline (189.348 us; speedup 1.0000x reference)
//
#include <hip/hip_runtime.h>
#include <stdint.h>

// Problem: out[M=2048(size_out), N=8192(batch)] = W[K,M]^T @ X[N,K]^T
//   out[m,n] = sum_k W[k,m] * X[n,k]
#define M_DIM 2048
#define N_DIM 8192
#define K_DIM 2048

typedef _Float16 f16x8 __attribute__((ext_vector_type(8)));
typedef _Float16 f16x4 __attribute__((ext_vector_type(4)));
typedef float    f32x4 __attribute__((ext_vector_type(4)));

// ---------------- fused prep: cvt X (blocks 0..8191) + transpose W (8192..12287) ----------------

__global__ __launch_bounds__(256) void prep(const float* __restrict__ X,
                                            const float* __restrict__ W,
                                            _Float16* __restrict__ Xb,
                                            _Float16* __restrict__ Wt) {
    __shared__ float tile[32][33];
    int b = blockIdx.x;
    if (b < 8192) {
        // X [N,K] fp32 -> Xb [N,K] f16, 8 elems/thread
        size_t i = ((size_t)b * 256 + threadIdx.x) * 8;
        float4 a = *(const float4*)(X + i);
        float4 c = *(const float4*)(X + i + 4);
        f16x8 h;
        h[0] = (_Float16)a.x; h[1] = (_Float16)a.y; h[2] = (_Float16)a.z; h[3] = (_Float16)a.w;
        h[4] = (_Float16)c.x; h[5] = (_Float16)c.y; h[6] = (_Float16)c.z; h[7] = (_Float16)c.w;
        *(f16x8*)(Xb + i) = h;
    } else {
        // W [K,M] fp32 -> Wt [M,K] f16, 32x32 tile
        b -= 8192;                         // 4096 blocks
        const int m0 = (b & 63) * 32;
        const int k0 = (b >> 6) * 32;
        const int tx = threadIdx.x & 31;
        const int ty = threadIdx.x >> 5;   // 0..7
#pragma unroll
        for (int i = 0; i < 32; i += 8)
            tile[ty + i][tx] = W[(size_t)(k0 + ty + i) * M_DIM + m0 + tx];  // tile[k][m]
        __syncthreads();
        const int ml = threadIdx.x >> 3;        // 0..31
        const int kg = (threadIdx.x & 7) * 4;   // 0..28
        f16x4 v;
#pragma unroll
        for (int j = 0; j < 4; ++j) v[j] = (_Float16)tile[kg + j][ml];
        *(f16x4*)(Wt + (size_t)(m0 + ml) * K_DIM + k0 + kg) = v;            // 8B store
    }
}

// ---------------- deep-pipelined 256x256 f16 MFMA GEMM, BK=32, ring-4 LDS ----------------
//
// T-stack port (learn_hip m196->m201): counted vmcnt (never 0 in main loop),
// raw s_barrier (no compiler-inserted vmcnt(0) drain), setprio around MFMA
// clusters, XOR-swizzled LDS, XCD-aware block swizzle.
//
// LDS ring: 4 slots x 32KB (A 16KB + B 16KB). Slot s = kt & 3.
//   A slot: 256 rows x 64B (32 f16). 16B chunk c of row r stored at chunk
//   c ^ ((r>>1)&3)  -> each ds_read_b128 wavefront access lands exactly 8
//   lanes per 4-bank group (conflict-free; verified lane math).
// Staging: global_load_lds writes linearly (tid*16 per 8KB issue); the SOURCE
//   k-chunk is pre-swizzled: cg = (tid&3) ^ ((tid>>3)&3)  (rule #21: swizzle
//   both sides via inverse-swizzled global address + linear LDS dest).
// Pipeline: tile T's compute issues staging for tile T+3 into slot (T+3)&3
//   (= (T-1)&3, freed at the preceding boundary barrier). Boundary wait is
//   vmcnt(8): tiles T+2,T+3 (4 loads each, per wave) stay in flight; tile T+1
//   forced complete. Epilogue drains 8 -> 4 -> 0.

__device__ __forceinline__ void load_to_lds16(const void* g, void* l) {
    __builtin_amdgcn_global_load_lds(
        (__attribute__((address_space(1))) void*)(uintptr_t)g,
        (__attribute__((address_space(3))) void*)l,
        16, 0, 0);
}

// stage one 256x32 f16 panel half-pair: 2 x global_load_lds (16B/lane, 512 thr)
__device__ __forceinline__ void stage_pair(const _Float16* g0, char* l0, int kt, int slot) {
    const _Float16* g = g0 + (size_t)kt * 32;
    char* d = l0 + slot * 32768;
    load_to_lds16(g, d);
    load_to_lds16(g + (size_t)128 * K_DIM, d + 8192);
}

#define BOUNDARY(N)                                                  \
    do {                                                             \
        asm volatile("s_waitcnt vmcnt(" #N ")" ::: "memory");        \
        __builtin_amdgcn_s_barrier();                                \
    } while (0)

template <int SLOT, int DSLOT, bool DO_STAGE>
__device__ __forceinline__ void tile_step(const char* lds, int aoff, int boff,
                                          const _Float16* ga, const _Float16* gb,
                                          char* lsa, char* lsb, int kstage,
                                          f32x4 (&acc)[8][4]) {
    const char* sa = lds + SLOT * 32768 + aoff;
    const char* sb = lds + SLOT * 32768 + boff;
    f16x8 af[4], bf[4];
    // ---- phase A: ds-reads (8 x b128) + A-panel staging, then 16 MFMA ----
#pragma unroll
    for (int ni = 0; ni < 4; ++ni) bf[ni] = *(const f16x8*)(sb + ni * 1024);
#pragma unroll
    for (int mi = 0; mi < 4; ++mi) af[mi] = *(const f16x8*)(sa + mi * 1024);
    if constexpr (DO_STAGE) stage_pair(ga, lsa, kstage, DSLOT);
    __builtin_amdgcn_s_barrier();
    __builtin_amdgcn_s_setprio(1);
#pragma unroll
    for (int mi = 0; mi < 4; ++mi)
#pragma unroll
        for (int ni = 0; ni < 4; ++ni)
            acc[mi][ni] = __builtin_amdgcn_mfma_f32_16x16x32_f16(af[mi], bf[ni], acc[mi][ni], 0, 0, 0);
    __builtin_amdgcn_s_setprio(0);
    // ---- phase B: ds-reads (4 x b128, mi 4..7) + B-panel staging, 16 MFMA ----
#pragma unroll
    for (int mi = 0; mi < 4; ++mi) af[mi] = *(const f16x8*)(sa + (mi + 4) * 1024);
    if constexpr (DO_STAGE) stage_pair(gb, lsb, kstage, DSLOT);
    __builtin_amdgcn_s_barrier();
    __builtin_amdgcn_s_setprio(1);
#pragma unroll
    for (int mi = 0; mi < 4; ++mi)
#pragma unroll
        for (int ni = 0; ni < 4; ++ni)
            acc[mi + 4][ni] = __builtin_amdgcn_mfma_f32_16x16x32_f16(af[mi], bf[ni], acc[mi + 4][ni], 0, 0, 0);
    __builtin_amdgcn_s_setprio(0);
}

// A = Wt [M,K] f16 (K-contiguous), B = Xb [N,K] f16 (K-contiguous), C [M,N] fp32
__global__ __launch_bounds__(512, 2) void gemm_f16_256(const _Float16* __restrict__ A,
                                                       const _Float16* __restrict__ B,
                                                       float* __restrict__ C) {
    extern __shared__ char lds[];          // 4 x 32KB ring = 128KB

    const int tid  = threadIdx.x;
    const int wave = tid >> 6;             // 0..7
    const int lane = tid & 63;
    const int lm = lane & 15, kq = lane >> 4;
    const int wm = wave >> 2, wn = wave & 3;   // 2x4 wave grid, each 128x64 of C

    // XCD swizzle: 256 blocks, 8 XCDs; XCD x gets bm = x (one 1MB A-panel,
    // L2-resident) x all 32 bn panels.
    const int bid = ((blockIdx.x & 7) << 5) | (blockIdx.x >> 3);
    const int bm = bid >> 5;               // 0..7
    const int bn = bid & 31;               // 0..31

    // staging addressing: issue i covers rows i*128 + (tid>>2), LDS chunk tid&3;
    // pre-swizzled global chunk cg = (tid&3) ^ ((tid>>3)&3)
    const int srow = tid >> 2;
    const int scg  = (tid & 3) ^ ((tid >> 3) & 3);
    const _Float16* ga = A + (size_t)(bm * 256 + srow) * K_DIM + scg * 8;
    const _Float16* gb = B + (size_t)(bn * 256 + srow) * K_DIM + scg * 8;
    char* lsa = lds + wave * 1024;                 // + slot*32768 (+8192 for issue 1)
    char* lsb = lds + 16384 + wave * 1024;

    // fragment read addressing: row R, global chunk kq lives at LDS chunk
    // kq ^ ((R>>1)&3); bits 1-2 of R come from lm only -> lane-constant swizzle
    const int swz  = (kq ^ ((lm >> 1) & 3)) << 4;
    const int aoff = (wm * 128 + lm) * 64 + swz;           // + mi*1024
    const int boff = 16384 + (wn * 64 + lm) * 64 + swz;    // + ni*1024

    f32x4 acc[8][4] = {};

    // prologue: stage tiles 0,1,2 (12 loads/wave); wait tile 0 (keep 8 in flight)
    stage_pair(ga, lsa, 0, 0); stage_pair(gb, lsb, 0, 0);
    stage_pair(ga, lsa, 1, 1); stage_pair(gb, lsb, 1, 1);
    stage_pair(ga, lsa, 2, 2); stage_pair(gb, lsb, 2, 2);
    asm volatile("s_waitcnt vmcnt(8)" ::: "memory");
    __builtin_amdgcn_s_barrier();

    // main loop: 60 tiles, slots fold to constants (kt = kt4*4)
#pragma unroll 1
    for (int kt4 = 0; kt4 < 15; ++kt4) {
        const int kt = kt4 * 4;
        tile_step<0, 3, true >(lds, aoff, boff, ga, gb, lsa, lsb, kt + 3, acc); BOUNDARY(8);
        tile_step<1, 0, true >(lds, aoff, boff, ga, gb, lsa, lsb, kt + 4, acc); BOUNDARY(8);
        tile_step<2, 1, true >(lds, aoff, boff, ga, gb, lsa, lsb, kt + 5, acc); BOUNDARY(8);
        tile_step<3, 2, true >(lds, aoff, boff, ga, gb, lsa, lsb, kt + 6, acc); BOUNDARY(8);
    }
    // tiles 60..63: stage last tile (63), then drain 8 -> 4 -> 0
    tile_step<0, 3, true >(lds, aoff, boff, ga, gb, lsa, lsb, 63, acc); BOUNDARY(8);
    tile_step<1, 0, false>(lds, aoff, boff, ga, gb, lsa, lsb, 0,  acc); BOUNDARY(4);
    tile_step<2, 0, false>(lds, aoff, boff, ga, gb, lsa, lsb, 0,  acc); BOUNDARY(0);
    tile_step<3, 0, false>(lds, aoff, boff, ga, gb, lsa, lsb, 0,  acc);

    // epilogue: D row (m) = kq*4 + reg, col (n) = lm  (verified 16x16 layout)
    const int cm0 = bm * 256 + wm * 128 + kq * 4;
    const int cn0 = bn * 256 + wn * 64 + lm;
#pragma unroll
    for (int mi = 0; mi < 8; ++mi)
#pragma unroll
        for (int ni = 0; ni < 4; ++ni) {
            float* cp = C + (size_t)(cm0 + mi * 16) * N_DIM + cn0 + ni * 16;
#pragma unroll
            for (int r = 0; r < 4; ++r) cp[(size_t)r * N_DIM] = acc[mi][ni][r];
        }
}

// ---------------- fp32 fallback (only if ws too small) ----------------

__global__ __launch_bounds__(256) void gemm_f32_fallback(const float* __restrict__ X,
                                                         const float* __restrict__ W,
                                                         float* __restrict__ C) {
    __shared__ float As2[16][64];  // As2[k][m]
    __shared__ float Bs2[16][64];  // Bs2[k][n]
    const int tid = threadIdx.x;
    const int bm = blockIdx.x & 31;
    const int bn = blockIdx.x >> 5;
    const int tm = tid & 15, tn = tid >> 4;
    float c[4][4] = {};
    for (int k0 = 0; k0 < K_DIM; k0 += 16) {
        __syncthreads();
#pragma unroll
        for (int i = 0; i < 4; ++i) {
            int e = i * 256 + tid;
            As2[e >> 6][e & 63] = W[(size_t)(k0 + (e >> 6)) * M_DIM + bm * 64 + (e & 63)];
        }
#pragma unroll
        for (int i = 0; i < 4; ++i) {
            int e = i * 256 + tid;
            Bs2[e & 15][e >> 4] = X[(size_t)(bn * 64 + (e >> 4)) * K_DIM + k0 + (e & 15)];
        }
        __syncthreads();
#pragma unroll
        for (int kk = 0; kk < 16; ++kk)
#pragma unroll
            for (int i = 0; i < 4; ++i)
#pragma unroll
                for (int j = 0; j < 4; ++j)
                    c[i][j] += As2[kk][tm * 4 + i] * Bs2[kk][tn * 4 + j];
    }
#pragma unroll
    for (int i = 0; i < 4; ++i)
#pragma unroll
        for (int j = 0; j < 4; ++j)
            C[(size_t)(bm * 64 + tm * 4 + i) * N_DIM + bn * 64 + tn * 4 + j] = c[i][j];
}

// ---------------- launch ----------------

extern "C" void kernel_launch(void* const* d_in, const int* in_sizes, int n_in,
                              void* d_out, int out_size, void* d_ws, size_t ws_size,
                              hipStream_t stream) {
    const float* X = (const float*)d_in[0];  // [8192, 2048]
    const float* W = (const float*)d_in[1];  // [2048, 2048]
    // d_in[2] = bias: intentionally unused (reference discards it)
    float* C = (float*)d_out;                // [2048, 8192]

    const size_t xb_bytes = (size_t)N_DIM * K_DIM * sizeof(_Float16);  // 32 MB
    const size_t wt_bytes = (size_t)M_DIM * K_DIM * sizeof(_Float16);  //  8 MB

    if (ws_size >= xb_bytes + wt_bytes) {
        static bool attr_set = false;
        if (!attr_set) {
            (void)hipFuncSetAttribute(reinterpret_cast<const void*>(gemm_f16_256),
                                      hipFuncAttributeMaxDynamicSharedMemorySize,
                                      131072);
            attr_set = true;
        }
        _Float16* Xb = (_Float16*)d_ws;
        _Float16* Wt = (_Float16*)((char*)d_ws + xb_bytes);
        prep<<<8192 + 4096, 256, 0, stream>>>(X, W, Xb, Wt);
        gemm_f16_256<<<(M_DIM / 256) * (N_DIM / 256), 512, 131072, stream>>>(Wt, Xb, C);
    } else {
        gemm_f32_fallback<<<(M_DIM / 64) * (N_DIM / 64), 256, 0, stream>>>(X, W, C);
    }
}

// Round 2
// 184.923 us; speedup vs baseline: 1.0239x; 1.0239x over previous
//
#include <hip/hip_runtime.h>
#include <stdint.h>

// Problem: out[M=2048(size_out), N=8192(batch)] = W[K,M]^T @ X[N,K]^T
//   out[m,n] = sum_k W[k,m] * X[n,k]
#define M_DIM 2048
#define N_DIM 8192
#define K_DIM 2048

typedef _Float16 f16x8 __attribute__((ext_vector_type(8)));
typedef _Float16 f16x4 __attribute__((ext_vector_type(4)));
typedef float    f32x4 __attribute__((ext_vector_type(4)));

// ---------------- fused prep: cvt X (blocks 0..8191) + transpose W (8192..12287) ----------------

__global__ __launch_bounds__(256) void prep(const float* __restrict__ X,
                                            const float* __restrict__ W,
                                            _Float16* __restrict__ Xb,
                                            _Float16* __restrict__ Wt) {
    __shared__ float tile[32][33];
    int b = blockIdx.x;
    if (b < 8192) {
        size_t i = ((size_t)b * 256 + threadIdx.x) * 8;
        float4 a = *(const float4*)(X + i);
        float4 c = *(const float4*)(X + i + 4);
        f16x8 h;
        h[0] = (_Float16)a.x; h[1] = (_Float16)a.y; h[2] = (_Float16)a.z; h[3] = (_Float16)a.w;
        h[4] = (_Float16)c.x; h[5] = (_Float16)c.y; h[6] = (_Float16)c.z; h[7] = (_Float16)c.w;
        *(f16x8*)(Xb + i) = h;
    } else {
        b -= 8192;
        const int m0 = (b & 63) * 32;
        const int k0 = (b >> 6) * 32;
        const int tx = threadIdx.x & 31;
        const int ty = threadIdx.x >> 5;
#pragma unroll
        for (int i = 0; i < 32; i += 8)
            tile[ty + i][tx] = W[(size_t)(k0 + ty + i) * M_DIM + m0 + tx];
        __syncthreads();
        const int ml = threadIdx.x >> 3;
        const int kg = (threadIdx.x & 7) * 4;
        f16x4 v;
#pragma unroll
        for (int j = 0; j < 4; ++j) v[j] = (_Float16)tile[kg + j][ml];
        *(f16x4*)(Wt + (size_t)(m0 + ml) * K_DIM + k0 + kg) = v;
    }
}

// ---------------- m201-style 256x256 f16 GEMM: BK=64, 2-slot dbuf, 4 quadrant phases ----------------
//
// LDS: 2 slots x 64KB (A 32KB rows p=0..255 x 128B, B 32KB). 16B-chunk XOR swizzle:
// LDS(p, c) holds global chunk c ^ (p&7) of global row r(p).
// Row-storage PERMUTATION (makes per-phase staging granularity race-free):
//   A: p = h*128 + wm*64 + q  <-> r = wm*128 + h*64 + q  (order: [0-63][128-191][64-127][192-255])
//   B: p = v*128 + wn*32 + q  <-> r = wn*64 + v*32 + q   (order: [0-31][64-95][128-159][192-223]...)
// so quadrant phase (h,v) reads touch ONLY A-half h and B-half v across all 8 waves.
// Staging: 8 issues/tile of 8KB (512thr x 16B), order A0,A0',B0,B0',B1,B1',A1,A1'
// issued 2-per-phase for tile T+1 during tile T. Waits: vmcnt(4) at phases 1-3
// (needed halves are always the oldest retired 2-4 loads), nothing at phase 4.
// 3 barriers + 3 counted vmcnt per K=64 (vs 6 barriers + full-tile waits before).

__device__ __forceinline__ void load_to_lds16(const void* g, void* l) {
    __builtin_amdgcn_global_load_lds(
        (__attribute__((address_space(1))) void*)(uintptr_t)g,
        (__attribute__((address_space(3))) void*)l,
        16, 0, 0);
}

template <int SLOT>
__device__ __forceinline__ void tile64(const char* lds, int pA, int pB,
                                       const _Float16* sa, const _Float16* sb,
                                       char* da, char* db, int snk,
                                       f32x4 (&acc)[8][4]) {
    constexpr int SB = SLOT * 65536;        // read slot base
    constexpr int NB = (SLOT ^ 1) * 65536;  // stage (next) slot base
    f16x8 af[2][4], bf[2][2];

    // ---- Ph1 (h=0, v=0); stage next A0 ----
    asm volatile("s_waitcnt vmcnt(4)" ::: "memory");
    __builtin_amdgcn_s_barrier();
#pragma unroll
    for (int kk = 0; kk < 2; ++kk) {
        const int kx = kk << 6;
#pragma unroll
        for (int mi = 0; mi < 4; ++mi)
            af[kk][mi] = *(const f16x8*)(lds + SB + mi * 2048 + (pA ^ kx));
#pragma unroll
        for (int ni = 0; ni < 2; ++ni)
            bf[kk][ni] = *(const f16x8*)(lds + SB + ni * 2048 + (pB ^ kx));
    }
    load_to_lds16(sa + snk,                         da + NB);
    load_to_lds16(sa + (size_t)128 * K_DIM + snk,   da + NB + 8192);
    __builtin_amdgcn_s_setprio(1);
#pragma unroll
    for (int kk = 0; kk < 2; ++kk)
#pragma unroll
        for (int mi = 0; mi < 4; ++mi)
#pragma unroll
            for (int ni = 0; ni < 2; ++ni)
                acc[mi][ni] = __builtin_amdgcn_mfma_f32_16x16x32_f16(af[kk][mi], bf[kk][ni], acc[mi][ni], 0, 0, 0);
    __builtin_amdgcn_s_setprio(0);

    // ---- Ph2 (h=0, v=1); stage next B0 ----
    asm volatile("s_waitcnt vmcnt(4)" ::: "memory");
    __builtin_amdgcn_s_barrier();
#pragma unroll
    for (int kk = 0; kk < 2; ++kk) {
        const int kx = kk << 6;
#pragma unroll
        for (int ni = 0; ni < 2; ++ni)
            bf[kk][ni] = *(const f16x8*)(lds + SB + 16384 + ni * 2048 + (pB ^ kx));
    }
    load_to_lds16(sb + snk,                         db + NB);
    load_to_lds16(sb + (size_t)128 * K_DIM + snk,   db + NB + 8192);
    __builtin_amdgcn_s_setprio(1);
#pragma unroll
    for (int kk = 0; kk < 2; ++kk)
#pragma unroll
        for (int mi = 0; mi < 4; ++mi)
#pragma unroll
            for (int ni = 0; ni < 2; ++ni)
                acc[mi][2 + ni] = __builtin_amdgcn_mfma_f32_16x16x32_f16(af[kk][mi], bf[kk][ni], acc[mi][2 + ni], 0, 0, 0);
    __builtin_amdgcn_s_setprio(0);

    // ---- Ph3 (h=1, v=0); stage next B1 ----
    asm volatile("s_waitcnt vmcnt(4)" ::: "memory");
    __builtin_amdgcn_s_barrier();
#pragma unroll
    for (int kk = 0; kk < 2; ++kk) {
        const int kx = kk << 6;
#pragma unroll
        for (int mi = 0; mi < 4; ++mi)
            af[kk][mi] = *(const f16x8*)(lds + SB + 16384 + mi * 2048 + (pA ^ kx));
#pragma unroll
        for (int ni = 0; ni < 2; ++ni)
            bf[kk][ni] = *(const f16x8*)(lds + SB + ni * 2048 + (pB ^ kx));
    }
    load_to_lds16(sb + (size_t)32 * K_DIM + snk,          db + NB + 16384);
    load_to_lds16(sb + (size_t)(128 + 32) * K_DIM + snk,  db + NB + 16384 + 8192);
    __builtin_amdgcn_s_setprio(1);
#pragma unroll
    for (int kk = 0; kk < 2; ++kk)
#pragma unroll
        for (int mi = 0; mi < 4; ++mi)
#pragma unroll
            for (int ni = 0; ni < 2; ++ni)
                acc[4 + mi][ni] = __builtin_amdgcn_mfma_f32_16x16x32_f16(af[kk][mi], bf[kk][ni], acc[4 + mi][ni], 0, 0, 0);
    __builtin_amdgcn_s_setprio(0);

    // ---- Ph4 (h=1, v=1); stage next A1 — no wait, no barrier ----
#pragma unroll
    for (int kk = 0; kk < 2; ++kk) {
        const int kx = kk << 6;
#pragma unroll
        for (int ni = 0; ni < 2; ++ni)
            bf[kk][ni] = *(const f16x8*)(lds + SB + 16384 + ni * 2048 + (pB ^ kx));
    }
    load_to_lds16(sa + (size_t)64 * K_DIM + snk,          da + NB + 16384);
    load_to_lds16(sa + (size_t)(128 + 64) * K_DIM + snk,  da + NB + 16384 + 8192);
    __builtin_amdgcn_s_setprio(1);
#pragma unroll
    for (int kk = 0; kk < 2; ++kk)
#pragma unroll
        for (int mi = 0; mi < 4; ++mi)
#pragma unroll
            for (int ni = 0; ni < 2; ++ni)
                acc[4 + mi][2 + ni] = __builtin_amdgcn_mfma_f32_16x16x32_f16(af[kk][mi], bf[kk][ni], acc[4 + mi][2 + ni], 0, 0, 0);
    __builtin_amdgcn_s_setprio(0);
}

// A = Wt [M,K] f16 (K-contiguous), B = Xb [N,K] f16 (K-contiguous), C [M,N] fp32
__global__ __launch_bounds__(512, 2) void gemm_f16_256(const _Float16* __restrict__ A,
                                                       const _Float16* __restrict__ B,
                                                       float* __restrict__ C) {
    extern __shared__ char lds[];          // 2 x 64KB

    const int tid  = threadIdx.x;
    const int wave = tid >> 6;
    const int lane = tid & 63;
    const int lm = lane & 15, kq = lane >> 4;
    const int wm = wave >> 2, wn = wave & 3;   // 2x4 wave grid, each 128x64 of C

    // XCD swizzle: XCD x owns bm = x (1MB A panel L2-resident) x all 32 bn
    const int bid = ((blockIdx.x & 7) << 5) | (blockIdx.x >> 3);
    const int bm = bid >> 5;               // 0..7
    const int bn = bid & 31;               // 0..31

    // staging source addressing (per-thread): t = source row-in-issue, cs = inverse-swizzled chunk
    const int t  = tid >> 3;                         // 0..63
    const int cs = ((tid & 7) ^ (t & 7)) * 8;        // f16 elems
    const _Float16* sa = A + (size_t)(bm * 256 + t) * K_DIM + cs;
    const _Float16* sb = B + (size_t)(bn * 256 + (t >> 5) * 64 + (t & 31)) * K_DIM + cs;
    char* da = lds + wave * 1024;           // A region; + slot*65536 + h*16384 + j*8192
    char* db = lds + 32768 + wave * 1024;   // B region

    // fragment read bases: row p = (h|v)*128 + (wm*64|wn*32) + (mi|ni)*16 + lm, chunk (kk*4+kq)^(lm&7)
    const int xr = lm & 7;
    const int pA = (wm * 64 + lm) * 128 + (kq ^ xr) * 16;            // + h*16384 + mi*2048, ^ (kk<<6)
    const int pB = 32768 + (wn * 32 + lm) * 128 + (kq ^ xr) * 16;    // + v*16384 + ni*2048, ^ (kk<<6)

    f32x4 acc[8][4] = {};

    // prologue: tile 0 into slot 0, issue order A0,A0',B0,B0',B1,B1',A1,A1'
    load_to_lds16(sa,                              da);
    load_to_lds16(sa + (size_t)128 * K_DIM,        da + 8192);
    load_to_lds16(sb,                              db);
    load_to_lds16(sb + (size_t)128 * K_DIM,        db + 8192);
    load_to_lds16(sb + (size_t)32 * K_DIM,         db + 16384);
    load_to_lds16(sb + (size_t)(128 + 32) * K_DIM, db + 16384 + 8192);
    load_to_lds16(sa + (size_t)64 * K_DIM,         da + 16384);
    load_to_lds16(sa + (size_t)(128 + 64) * K_DIM, da + 16384 + 8192);

    // main loop: 32 tiles of K=64, slot alternates; staging targets tile kt+1 (wrap -> dead data)
#pragma unroll 1
    for (int t2 = 0; t2 < 16; ++t2) {
        const int kt = t2 * 2;
        tile64<0>(lds, pA, pB, sa, sb, da, db, (kt + 1) * 64, acc);
        tile64<1>(lds, pA, pB, sa, sb, da, db, ((kt + 2) & 31) * 64, acc);
    }

    // epilogue: D row (m) = kq*4 + reg, col (n) = lm  (verified 16x16 layout)
    const int cm0 = bm * 256 + wm * 128 + kq * 4;
    const int cn0 = bn * 256 + wn * 64 + lm;
#pragma unroll
    for (int mi = 0; mi < 8; ++mi)
#pragma unroll
        for (int ni = 0; ni < 4; ++ni) {
            float* cp = C + (size_t)(cm0 + mi * 16) * N_DIM + cn0 + ni * 16;
#pragma unroll
            for (int r = 0; r < 4; ++r) cp[(size_t)r * N_DIM] = acc[mi][ni][r];
        }
}

// ---------------- fp32 fallback (only if ws too small) ----------------

__global__ __launch_bounds__(256) void gemm_f32_fallback(const float* __restrict__ X,
                                                         const float* __restrict__ W,
                                                         float* __restrict__ C) {
    __shared__ float As2[16][64];
    __shared__ float Bs2[16][64];
    const int tid = threadIdx.x;
    const int bm = blockIdx.x & 31;
    const int bn = blockIdx.x >> 5;
    const int tm = tid & 15, tn = tid >> 4;
    float c[4][4] = {};
    for (int k0 = 0; k0 < K_DIM; k0 += 16) {
        __syncthreads();
#pragma unroll
        for (int i = 0; i < 4; ++i) {
            int e = i * 256 + tid;
            As2[e >> 6][e & 63] = W[(size_t)(k0 + (e >> 6)) * M_DIM + bm * 64 + (e & 63)];
        }
#pragma unroll
        for (int i = 0; i < 4; ++i) {
            int e = i * 256 + tid;
            Bs2[e & 15][e >> 4] = X[(size_t)(bn * 64 + (e >> 4)) * K_DIM + k0 + (e & 15)];
        }
        __syncthreads();
#pragma unroll
        for (int kk = 0; kk < 16; ++kk)
#pragma unroll
            for (int i = 0; i < 4; ++i)
#pragma unroll
                for (int j = 0; j < 4; ++j)
                    c[i][j] += As2[kk][tm * 4 + i] * Bs2[kk][tn * 4 + j];
    }
#pragma unroll
    for (int i = 0; i < 4; ++i)
#pragma unroll
        for (int j = 0; j < 4; ++j)
            C[(size_t)(bm * 64 + tm * 4 + i) * N_DIM + bn * 64 + tn * 4 + j] = c[i][j];
}

// ---------------- launch ----------------

extern "C" void kernel_launch(void* const* d_in, const int* in_sizes, int n_in,
                              void* d_out, int out_size, void* d_ws, size_t ws_size,
                              hipStream_t stream) {
    const float* X = (const float*)d_in[0];  // [8192, 2048]
    const float* W = (const float*)d_in[1];  // [2048, 2048]
    // d_in[2] = bias: intentionally unused (reference discards it)
    float* C = (float*)d_out;                // [2048, 8192]

    const size_t xb_bytes = (size_t)N_DIM * K_DIM * sizeof(_Float16);  // 32 MB
    const size_t wt_bytes = (size_t)M_DIM * K_DIM * sizeof(_Float16);  //  8 MB

    if (ws_size >= xb_bytes + wt_bytes) {
        static bool attr_set = false;
        if (!attr_set) {
            (void)hipFuncSetAttribute(reinterpret_cast<const void*>(gemm_f16_256),
                                      hipFuncAttributeMaxDynamicSharedMemorySize,
                                      131072);
            attr_set = true;
        }
        _Float16* Xb = (_Float16*)d_ws;
        _Float16* Wt = (_Float16*)((char*)d_ws + xb_bytes);
        prep<<<8192 + 4096, 256, 0, stream>>>(X, W, Xb, Wt);
        gemm_f16_256<<<(M_DIM / 256) * (N_DIM / 256), 512, 131072, stream>>>(Wt, Xb, C);
    } else {
        gemm_f32_fallback<<<(M_DIM / 64) * (N_DIM / 64), 256, 0, stream>>>(X, W, C);
    }
}